// Round 15
// baseline (263.158 us; speedup 1.0000x reference)
//
#include <hip/hip_runtime.h>
#include <hip/hip_bf16.h>

#define IN_F  128
#define HID_F 256
#define OUT_F 64
#define BUCKET_SHIFT 9
#define BUCKET_SZ 512
#define EPB 16384           // edges per binning block (1024 threads, 16 iters)
#define CAP 10240           // fixed bucket capacity (mean 8190, +22 sigma)

typedef __attribute__((ext_vector_type(8))) short bf16x8;
typedef __attribute__((ext_vector_type(4))) float f32x4;

__device__ __forceinline__ float bf2f(unsigned short u) {
    union { unsigned int i; float f; } v; v.i = ((unsigned int)u) << 16; return v.f;
}
__device__ __forceinline__ float bf2f_lo(unsigned int p) {
    union { unsigned int i; float f; } v; v.i = p << 16; return v.f;
}
__device__ __forceinline__ float bf2f_hi(unsigned int p) {
    union { unsigned int i; float f; } v; v.i = p & 0xffff0000u; return v.f;
}
__device__ __forceinline__ unsigned short f2bf(float f) {
    __hip_bfloat16 b = __float2bfloat16(f);
    return *reinterpret_cast<unsigned short*>(&b);
}

// ---- W12 = W1@W2 (swizzled, B-frag order), 8 blocks ---------------------
// Full linearity: out = (I+A)^2 (x @ W12). W12 is 128x64.
__global__ __launch_bounds__(1024) void k_w12(
    const float* __restrict__ W1, const float* __restrict__ W2,
    unsigned short* __restrict__ w12s)
{
    // chunk c=nt*4+ks; lane L; elem j: k=ks*32+(L>>4)*8+j, n=nt*16+(L&15)
    int idx = blockIdx.x * 1024 + threadIdx.x;   // 0..8191
    int c = idx >> 9, L = (idx >> 3) & 63, j = idx & 7;
    int nt = c >> 2, ks = c & 3;
    int k = ks * 32 + (L >> 4) * 8 + j;
    int n = nt * 16 + (L & 15);
    float s = 0.f;
    #pragma unroll 8
    for (int jj = 0; jj < HID_F; ++jj)
        s += W1[k * HID_F + jj] * W2[jj * OUT_F + n];
    w12s[idx] = f2bf(s);
}

// ---- Mega: bin (blocks 0..A-1) | y_gemm (blocks A..) --------------------
// bin: LDS hist -> one global atomicAdd per (block,bucket) reserves a
// contiguous run in bucket region b*CAP -> scatter packed records.
// pack = (dlocal<<23) | src  (dlocal 9 bits, src < 2^17).
// y:   y[M,64] = x[M,128] @ W12, fp32 in, bf16 out (256 nodes/block).
// The two branches are independent; bin's atomic-latency stalls hide
// under y's streaming BW on shared CUs.
__global__ __launch_bounds__(1024) void k_mega(
    const int* __restrict__ esrc, const int* __restrict__ edst,
    int* __restrict__ gcur, unsigned int* __restrict__ binned, int nEdges, int A,
    const float* __restrict__ x, const unsigned short* __restrict__ w12s,
    unsigned short* __restrict__ y, int nNodes)
{
    __shared__ int hist[256];   // NB <= 256
    __shared__ int lcur[256];
    int bid = blockIdx.x;
    int t = threadIdx.x;
    if (bid < A) {
        // ---- bin branch ----
        if (t < 256) hist[t] = 0;
        __syncthreads();
        long long base = (long long)bid * EPB;
        #pragma unroll
        for (int k = 0; k < EPB / 1024; ++k) {
            long long e = base + k * 1024 + t;
            if (e < nEdges) atomicAdd(&hist[edst[e] >> BUCKET_SHIFT], 1);
        }
        __syncthreads();
        if (t < 256) {
            int h = hist[t];
            lcur[t] = (h > 0) ? atomicAdd(&gcur[t], h) : 0;
        }
        __syncthreads();
        #pragma unroll
        for (int k = 0; k < EPB / 1024; ++k) {
            long long e = base + k * 1024 + t;
            if (e < nEdges) {
                int s = esrc[e], d = edst[e];
                int b = d >> BUCKET_SHIFT;
                int pos = atomicAdd(&lcur[b], 1);
                binned[(size_t)b * CAP + pos] =
                    (((unsigned int)(d & (BUCKET_SZ - 1))) << 23) | (unsigned int)s;
            }
        }
    } else {
        // ---- y_gemm branch: 16 waves, 16 rows each (256 nodes/block) ----
        int wave = t >> 6, lane = t & 63;
        int m0 = (bid - A) * 256 + wave * 16;
        if (m0 >= nNodes) return;
        int row = lane & 15, quad = lane >> 4;
        int rr = min(m0 + row, nNodes - 1);      // clamp tail reads in-bounds
        const float* aRow = x + (size_t)rr * IN_F + quad * 8;
        f32x4 acc[4] = {};
        const bf16x8* bBase = reinterpret_cast<const bf16x8*>(w12s) + lane;
        #pragma unroll
        for (int ks = 0; ks < 4; ++ks) {
            float4 a0 = *reinterpret_cast<const float4*>(aRow + ks * 32);
            float4 a1 = *reinterpret_cast<const float4*>(aRow + ks * 32 + 4);
            bf16x8 a;
            a[0] = (short)f2bf(a0.x); a[1] = (short)f2bf(a0.y);
            a[2] = (short)f2bf(a0.z); a[3] = (short)f2bf(a0.w);
            a[4] = (short)f2bf(a1.x); a[5] = (short)f2bf(a1.y);
            a[6] = (short)f2bf(a1.z); a[7] = (short)f2bf(a1.w);
            #pragma unroll
            for (int nt = 0; nt < 4; ++nt) {
                bf16x8 b = bBase[(nt * 4 + ks) * 64];
                acc[nt] = __builtin_amdgcn_mfma_f32_16x16x32_bf16(a, b, acc[nt], 0, 0, 0);
            }
        }
        size_t outBase = (size_t)(m0 + quad * 4) * OUT_F + row;
        #pragma unroll
        for (int i = 0; i < 4; ++i) {
            if (m0 + quad * 4 + i >= nNodes) break;   // tail guard
            #pragma unroll
            for (int nt = 0; nt < 4; ++nt)
                y[outBase + (size_t)i * OUT_F + nt * 16] = f2bf(acc[nt][i]);
        }
    }
}

// ---- Per-bucket local CSR (512 threads, 1 thread/node) ------------------
__global__ __launch_bounds__(512) void k_localcsr(
    const unsigned int* __restrict__ binned, const int* __restrict__ gcur,
    int* __restrict__ rowbeg, int* __restrict__ rowend,
    int* __restrict__ eidx, int nNodes)
{
    __shared__ int ldeg[BUCKET_SZ];
    __shared__ int lscan[BUCKET_SZ];
    int t = threadIdx.x;          // 0..511
    ldeg[t] = 0;
    __syncthreads();
    int eb0 = blockIdx.x * CAP;
    int cnt = gcur[blockIdx.x];
    int node0 = blockIdx.x << BUCKET_SHIFT;
    for (int e = t; e < cnt; e += 512)
        atomicAdd(&ldeg[binned[eb0 + e] >> 23], 1);
    __syncthreads();
    int s = ldeg[t];
    lscan[t] = s;
    __syncthreads();
    for (int d = 1; d < 512; d <<= 1) {
        int add = (t >= d) ? lscan[t - d] : 0;
        __syncthreads();
        lscan[t] += add;
        __syncthreads();
    }
    int excl = lscan[t] - s;
    int n0 = node0 + t;
    if (n0 < nNodes) { rowbeg[n0] = eb0 + excl; rowend[n0] = eb0 + excl + s; }
    __syncthreads();
    ldeg[t] = excl;               // becomes local cursor
    __syncthreads();
    for (int e = t; e < cnt; e += 512) {
        unsigned int p = binned[eb0 + e];
        int dl = (int)(p >> 23), sv = (int)(p & 0x7fffffu);
        int pos = atomicAdd(&ldeg[dl], 1);
        eidx[eb0 + pos] = sv;
    }
}

// ---- Layer-1 gather (64-dim): aggy[n] = y[n] + sum y[src], bf16 out -----
// Wide-gather: 8 lanes cover a 128B row (dwordx4/lane) -> 8 edges/instr.
__global__ __launch_bounds__(256) void gather1y(
    const unsigned short* __restrict__ y, const int* __restrict__ rowbeg,
    const int* __restrict__ rowend,
    const int* __restrict__ eidx, unsigned short* __restrict__ aggy, int nNodes)
{
    int n    = blockIdx.x * 4 + __builtin_amdgcn_readfirstlane(threadIdx.x >> 6);
    int lane = threadIdx.x & 63;
    if (n >= nNodes) return;
    int beg = __builtin_amdgcn_readfirstlane(rowbeg[n]);
    int end = __builtin_amdgcn_readfirstlane(rowend[n]);
    int g = lane >> 3;          // edge subgroup 0..7
    int f = lane & 7;           // 16B chunk within row
    float acc[8] = {0.f, 0.f, 0.f, 0.f, 0.f, 0.f, 0.f, 0.f};

    for (int e0 = beg; e0 < end; e0 += 64) {
        int cnt = min(64, end - e0);                 // uniform
        int e = (lane < cnt) ? eidx[e0 + lane] : 0;
        for (int i = 0; i < cnt; i += 32) {          // 32 edges per block
            uint4 v[4];
            unsigned int vmask[4];
            #pragma unroll
            for (int j = 0; j < 4; ++j) {
                int eij = i + 8 * j + g;
                int src = __builtin_amdgcn_ds_bpermute(eij << 2, e);
                int s0  = __builtin_amdgcn_readlane(e, i + 8 * j);
                bool valid = eij < cnt;
                vmask[j] = valid ? 0xffffffffu : 0u;
                src = valid ? src : s0;
                v[j] = *reinterpret_cast<const uint4*>(
                    y + (unsigned)src * OUT_F + (f << 3));
            }
            #pragma unroll
            for (int j = 0; j < 4; ++j) {
                unsigned int a0 = v[j].x & vmask[j], a1 = v[j].y & vmask[j];
                unsigned int a2 = v[j].z & vmask[j], a3 = v[j].w & vmask[j];
                acc[0] += bf2f_lo(a0); acc[1] += bf2f_hi(a0);
                acc[2] += bf2f_lo(a1); acc[3] += bf2f_hi(a1);
                acc[4] += bf2f_lo(a2); acc[5] += bf2f_hi(a2);
                acc[6] += bf2f_lo(a3); acc[7] += bf2f_hi(a3);
            }
        }
    }
    // cross-subgroup reduce (8 groups share feature chunks)
    #pragma unroll
    for (int k = 0; k < 8; ++k) {
        acc[k] += __shfl_xor(acc[k], 8);
        acc[k] += __shfl_xor(acc[k], 16);
        acc[k] += __shfl_xor(acc[k], 32);
    }
    // self row add
    uint4 sv = *reinterpret_cast<const uint4*>(y + (size_t)n * OUT_F + (f << 3));
    acc[0] += bf2f_lo(sv.x); acc[1] += bf2f_hi(sv.x);
    acc[2] += bf2f_lo(sv.y); acc[3] += bf2f_hi(sv.y);
    acc[4] += bf2f_lo(sv.z); acc[5] += bf2f_hi(sv.z);
    acc[6] += bf2f_lo(sv.w); acc[7] += bf2f_hi(sv.w);
    if (g == 0) {
        uint4 o;
        o.x = (unsigned int)f2bf(acc[0]) | ((unsigned int)f2bf(acc[1]) << 16);
        o.y = (unsigned int)f2bf(acc[2]) | ((unsigned int)f2bf(acc[3]) << 16);
        o.z = (unsigned int)f2bf(acc[4]) | ((unsigned int)f2bf(acc[5]) << 16);
        o.w = (unsigned int)f2bf(acc[6]) | ((unsigned int)f2bf(acc[7]) << 16);
        *reinterpret_cast<uint4*>(aggy + (size_t)n * OUT_F + (f << 3)) = o;
    }
}

// ---- Layer-2 gather: out[n] = aggy[n] + sum aggy[src], fp32 out ---------
__global__ __launch_bounds__(256) void gather2(
    const unsigned short* __restrict__ aggy, const int* __restrict__ rowbeg,
    const int* __restrict__ rowend,
    const int* __restrict__ eidx, float* __restrict__ out, int nNodes)
{
    int n    = blockIdx.x * 4 + __builtin_amdgcn_readfirstlane(threadIdx.x >> 6);
    int lane = threadIdx.x & 63;
    if (n >= nNodes) return;
    int beg = __builtin_amdgcn_readfirstlane(rowbeg[n]);
    int end = __builtin_amdgcn_readfirstlane(rowend[n]);
    int g = lane >> 3;          // edge subgroup 0..7
    int f = lane & 7;           // 16B chunk within row
    float acc[8] = {0.f, 0.f, 0.f, 0.f, 0.f, 0.f, 0.f, 0.f};

    for (int e0 = beg; e0 < end; e0 += 64) {
        int cnt = min(64, end - e0);                 // uniform
        int e = (lane < cnt) ? eidx[e0 + lane] : 0;
        for (int i = 0; i < cnt; i += 32) {          // 32 edges per block
            uint4 v[4];
            unsigned int vmask[4];
            #pragma unroll
            for (int j = 0; j < 4; ++j) {
                int eij = i + 8 * j + g;
                int src = __builtin_amdgcn_ds_bpermute(eij << 2, e);
                int s0  = __builtin_amdgcn_readlane(e, i + 8 * j);
                bool valid = eij < cnt;
                vmask[j] = valid ? 0xffffffffu : 0u;
                src = valid ? src : s0;
                v[j] = *reinterpret_cast<const uint4*>(
                    aggy + (unsigned)src * OUT_F + (f << 3));
            }
            #pragma unroll
            for (int j = 0; j < 4; ++j) {
                unsigned int a0 = v[j].x & vmask[j], a1 = v[j].y & vmask[j];
                unsigned int a2 = v[j].z & vmask[j], a3 = v[j].w & vmask[j];
                acc[0] += bf2f_lo(a0); acc[1] += bf2f_hi(a0);
                acc[2] += bf2f_lo(a1); acc[3] += bf2f_hi(a1);
                acc[4] += bf2f_lo(a2); acc[5] += bf2f_hi(a2);
                acc[6] += bf2f_lo(a3); acc[7] += bf2f_hi(a3);
            }
        }
    }
    // cross-subgroup reduce (8 groups share feature chunks)
    #pragma unroll
    for (int k = 0; k < 8; ++k) {
        acc[k] += __shfl_xor(acc[k], 8);
        acc[k] += __shfl_xor(acc[k], 16);
        acc[k] += __shfl_xor(acc[k], 32);
    }
    // self row add
    uint4 sv = *reinterpret_cast<const uint4*>(aggy + (size_t)n * OUT_F + (f << 3));
    acc[0] += bf2f_lo(sv.x); acc[1] += bf2f_hi(sv.x);
    acc[2] += bf2f_lo(sv.y); acc[3] += bf2f_hi(sv.y);
    acc[4] += bf2f_lo(sv.z); acc[5] += bf2f_hi(sv.z);
    acc[6] += bf2f_lo(sv.w); acc[7] += bf2f_hi(sv.w);
    if (g == 0) {
        float* o = out + (size_t)n * OUT_F + (f << 3);
        *reinterpret_cast<float4*>(o)     = make_float4(acc[0], acc[1], acc[2], acc[3]);
        *reinterpret_cast<float4*>(o + 4) = make_float4(acc[4], acc[5], acc[6], acc[7]);
    }
}

extern "C" void kernel_launch(void* const* d_in, const int* in_sizes, int n_in,
                              void* d_out, int out_size, void* d_ws, size_t ws_size,
                              hipStream_t stream) {
    const float* x  = (const float*)d_in[0];
    const int* esrc = (const int*)d_in[1];
    const int* edst = (const int*)d_in[2];
    const float* W1 = (const float*)d_in[3];
    const float* W2 = (const float*)d_in[4];
    float* out      = (float*)d_out;

    const int nNodes = in_sizes[0] / IN_F;
    const int nEdges = in_sizes[1];
    const int NB = (nNodes + BUCKET_SZ - 1) / BUCKET_SZ;   // 196 (<= 256)
    const int A  = (nEdges + EPB - 1) / EPB;               // 98 binning blocks

    // Workspace (~42 MB; 110.4 MB known-safe), 64B-aligned segments.
    char* ws = (char*)d_ws;
    size_t off = 0;
    auto alloc = [&](size_t bytes) {
        char* p = ws + off; off = (off + bytes + 63) & ~(size_t)63; return p;
    };
    unsigned short* y    = (unsigned short*)alloc((size_t)nNodes * OUT_F * 2);
    unsigned short* aggy = (unsigned short*)alloc((size_t)nNodes * OUT_F * 2);
    unsigned int* binned = (unsigned int*)alloc((size_t)NB * CAP * 4);
    int* eidx            = (int*)alloc((size_t)NB * CAP * 4);
    unsigned short* w12s = (unsigned short*)alloc((size_t)IN_F * OUT_F * 2);
    int* rowbeg          = (int*)alloc((size_t)nNodes * 4);
    int* rowend          = (int*)alloc((size_t)nNodes * 4);
    int* gcur            = (int*)alloc(256 * 4);

    hipMemsetAsync(gcur, 0, 256 * 4, stream);

    k_w12<<<8, 1024, 0, stream>>>(W1, W2, w12s);

    // ---- mega: bin | y_gemm (bin blocks first, y fills behind) ----
    const int yBlocks = (nNodes + 255) / 256;              // 391
    k_mega<<<A + yBlocks, 1024, 0, stream>>>(
        esrc, edst, gcur, binned, nEdges, A, x, w12s, y, nNodes);

    k_localcsr<<<NB, 512, 0, stream>>>(binned, gcur, rowbeg, rowend, eidx, nNodes);

    const int nBlocks = (nNodes + 3) / 4;
    gather1y<<<nBlocks, 256, 0, stream>>>(y, rowbeg, rowend, eidx, aggy, nNodes);
    gather2<<<nBlocks, 256, 0, stream>>>(aggy, rowbeg, rowend, eidx, out, nNodes);
}